// Round 2
// baseline (636.636 us; speedup 1.0000x reference)
//
#include <hip/hip_runtime.h>

// QuantizedLinear: out[M,N] = (rowquant(x) . W_q) * a_scale[M] * w_scale[N] + bias[N]
// M=8192, K=4096, N=4096.  Two kernels:
//  1) prep_kernel:   fused {per-row absmax quant -> x_q int8 [M,K]} + {W_q int32 [K,N]
//                    -> int8 [N,K] transpose-pack} (independent block ranges, one launch)
//  2) gemm_i8_kernel: 256x256x128 tile, 8-phase READ-AHEAD schedule (T1+T2+T3/T4+T5),
//                    mfma_i32_16x16x64_i8; every ds_read issued >=1 phase before its
//                    consuming MFMA; counted vmcnt(4)/(2); XOR-swizzled LDS.

typedef int int32x4 __attribute__((ext_vector_type(4)));

#define TILE_BM 256
#define TILE_BN 256
#define TILE_BK 128   // int8 k-depth per K-tile (2 mfma k-steps of 64)

__device__ __forceinline__ void async_copy16(const void* g, void* l) {
    __builtin_amdgcn_global_load_lds(
        (const __attribute__((address_space(1))) unsigned int*)g,
        (__attribute__((address_space(3))) unsigned int*)l,
        16, 0, 0);
}

__device__ __forceinline__ int quant1(float x, float s) {
    float q = rintf(x / s);               // true division: bit-match np (x / a_scale)
    q = fminf(127.0f, fmaxf(-128.0f, q)); // np.clip(round, -128, 127)
    return (int)q;
}

// ---------------- kernel 1: fused quant + transpose-pack ----------------
// blocks [0, M)            : per-row dynamic quantization (row = blockIdx.x)
// blocks [M, M + N/64*K/64): weight transpose-pack 64x64 tile
__global__ __launch_bounds__(256) void prep_kernel(
    const float* __restrict__ x, signed char* __restrict__ xq, float* __restrict__ ascale,
    const int* __restrict__ Bq, signed char* __restrict__ Bt, int K, int N, int M)
{
    __shared__ float wmax[4];
    __shared__ int lds[64 * 17]; // [n_local 0..63][k-dword 0..15] + pad
    const int t = threadIdx.x;

    if ((int)blockIdx.x < M) {
        // ---- quant: one row of K=4096 floats, 16 per thread, wave-coalesced
        const int row = blockIdx.x;
        const float4* xr4 = (const float4*)(x + (size_t)row * K);

        float4 v[4];
        float mx = 0.0f;
#pragma unroll
        for (int i = 0; i < 4; ++i) {
            v[i] = xr4[i * 256 + t];
            mx = fmaxf(mx, fmaxf(fmaxf(fabsf(v[i].x), fabsf(v[i].y)),
                                 fmaxf(fabsf(v[i].z), fabsf(v[i].w))));
        }
#pragma unroll
        for (int off = 32; off > 0; off >>= 1)
            mx = fmaxf(mx, __shfl_xor(mx, off, 64));
        if ((t & 63) == 0) wmax[t >> 6] = mx;
        __syncthreads();
        mx = fmaxf(fmaxf(wmax[0], wmax[1]), fmaxf(wmax[2], wmax[3]));

        const float s = fmaxf(mx / 127.0f, 1e-8f);
        if (t == 0) ascale[row] = s;

        int* xqr = (int*)(xq + (size_t)row * K);
#pragma unroll
        for (int i = 0; i < 4; ++i) {
            const int b0 = quant1(v[i].x, s);
            const int b1 = quant1(v[i].y, s);
            const int b2 = quant1(v[i].z, s);
            const int b3 = quant1(v[i].w, s);
            xqr[i * 256 + t] = (b0 & 255) | ((b1 & 255) << 8) | ((b2 & 255) << 16) | ((b3 & 255) << 24);
        }
    } else {
        // ---- transpose-pack: W_q int32 [K,N] -> int8 [N,K], 64x64 tile
        const int tb = (int)blockIdx.x - M;
        const int nbx = N >> 6;
        const int n0 = (tb % nbx) * 64;
        const int k0 = (tb / nbx) * 64;

        const int r = t >> 4;            // k-dword index 0..15 -> k rows 4r..4r+3
        const int ncol = (t & 15) * 4;   // n offset 0,4,...,60

        const int* src = Bq + (size_t)(k0 + 4 * r) * N + n0 + ncol;
        const int4 u0 = *(const int4*)(src);
        const int4 u1 = *(const int4*)(src + N);
        const int4 u2 = *(const int4*)(src + 2 * (size_t)N);
        const int4 u3 = *(const int4*)(src + 3 * (size_t)N);

        lds[(ncol + 0) * 17 + r] = (u0.x & 255) | ((u1.x & 255) << 8) | ((u2.x & 255) << 16) | ((u3.x & 255) << 24);
        lds[(ncol + 1) * 17 + r] = (u0.y & 255) | ((u1.y & 255) << 8) | ((u2.y & 255) << 16) | ((u3.y & 255) << 24);
        lds[(ncol + 2) * 17 + r] = (u0.z & 255) | ((u1.z & 255) << 8) | ((u2.z & 255) << 16) | ((u3.z & 255) << 24);
        lds[(ncol + 3) * 17 + r] = (u0.w & 255) | ((u1.w & 255) << 8) | ((u2.w & 255) << 16) | ((u3.w & 255) << 24);
        __syncthreads();

        const int nl = t >> 2, ch = t & 3;
        int o[4];
#pragma unroll
        for (int i = 0; i < 4; ++i) o[i] = lds[nl * 17 + ch * 4 + i];
        *(int32x4*)(Bt + (size_t)(n0 + nl) * K + k0 + ch * 16) = *(const int32x4*)o;
    }
}

// ---------------- kernel 2: int8 GEMM, 256x256 tile, 8-phase read-ahead ----------------
// A = x_q [M,K] int8, B = Bt [N,K] int8 (k-contiguous).
// 512 threads = 8 waves (2 M x 4 N); per-wave output 128x64 = 8x4 frags of 16x16.
// LDS 128 KiB: 2 slots x (A 32KB + B 32KB); slot0 = even K-tiles, slot1 = odd.
// Quadrant order per slot: QA=a0*b01, QB=a1*b01, QC=a0*b23, QD=a1*b23 -- each register
// buffer's last use is exactly one phase before its refill, so EVERY ds_read is issued
// one phase ahead of its consuming MFMA (reads/phase = 8,4,4,8 vs 16 MFMA/phase):
//   P1 QA(s0) | rd RA1(s0)      | stage s1.A.h0(2i+1)
//   P2 QB(s0) | rd RB23(s0)     | stage s1.A.h1(2i+1) | LGKM0, vmcnt(4)
//   P3 QC(s0) | rd RB01(s1)     | stage s0.B.h0(2i+2) | vmcnt(2)
//   P4 QD(s0) | rd RA0(s1)      | stage s0.B.h1(2i+2)
//   P5 QA(s1) | rd RA1(s1)      | stage s0.A.h0(2i+2)
//   P6 QB(s1) | rd RB23(s1)     | stage s0.A.h1(2i+2) | LGKM0, vmcnt(4)
//   P7 QC(s1) | rd RB01(s0')    | stage s1.B.h0(2i+3) | vmcnt(2)
//   P8 QD(s1) | rd RA0(s0')     | stage s1.B.h1(2i+3)
// vmcnt is counted (never 0 mid-loop): vmcnt(4)@P2/P6 tails lands the B halves read 1
// phase later; vmcnt(2)@P3/P7 tails lands the A halves read 1 phase later. LGKM0@P2/P6
// tails closes the RB23-read vs next-phase-stage WAR window. LDS swizzle: byte ^=
// ((row&7)<<4) on ds_read addr AND pre-applied on the global source chunk (rule 21).

#define SBAR() do { asm volatile("" ::: "memory"); __builtin_amdgcn_s_barrier(); asm volatile("" ::: "memory"); } while (0)
#define LGKM0() asm volatile("s_waitcnt lgkmcnt(0)" ::: "memory")
#define VMCNT(n) asm volatile("s_waitcnt vmcnt(" #n ")" ::: "memory")

#define MFMA_Q(AF, MB, NB)                                                              \
    do {                                                                                \
        __builtin_amdgcn_s_setprio(1);                                                  \
        _Pragma("unroll") for (int mm = 0; mm < 4; ++mm) {                              \
            _Pragma("unroll") for (int nn = 0; nn < 2; ++nn) {                          \
                int32x4 v = acc[(MB) + mm][(NB) + nn];                                  \
                v = __builtin_amdgcn_mfma_i32_16x16x64_i8(AF[mm][0], b[(NB) + nn][0], v, 0, 0, 0); \
                v = __builtin_amdgcn_mfma_i32_16x16x64_i8(AF[mm][1], b[(NB) + nn][1], v, 0, 0, 0); \
                acc[(MB) + mm][(NB) + nn] = v;                                          \
            }                                                                           \
        }                                                                               \
        __builtin_amdgcn_s_setprio(0);                                                  \
    } while (0)

__global__ __launch_bounds__(512, 2) void gemm_i8_kernel(
    const signed char* __restrict__ Aq, const signed char* __restrict__ Bt,
    const float* __restrict__ ascale, const float* __restrict__ wscale,
    const float* __restrict__ bias, float* __restrict__ C,
    int M, int N, int K)
{
    __shared__ __align__(16) signed char smem[131072]; // [slot:2][A 32K | B 32K]

    const int t = threadIdx.x;
    const int lane = t & 63;
    const int w = t >> 6;            // 0..7
    const int wr = w >> 2;           // 0..1 (M)
    const int wc = w & 3;            // 0..3 (N)
    const int ml = lane & 15, kq = lane >> 4;
    const int lr = lane >> 3, l8 = lane & 7;

    // T1: XCD-aware block swizzle (nwg = 512, divisible by 8)
    const int nbx = gridDim.x;       // N/256
    int bid = blockIdx.y * nbx + blockIdx.x;
    const int nwg = nbx * gridDim.y;
    if ((nwg & 7) == 0) bid = (bid & 7) * (nwg >> 3) + (bid >> 3);
    const int m0 = (bid / nbx) * TILE_BM;
    const int n0 = (bid % nbx) * TILE_BN;

    // ---- staging: per half (128 rows x 128B = 16KB), thread does 2x16B loads.
    const int srow = w * 8 + lr;                 // 0..63
    const int stoff = srow * 128 + l8 * 16;      // within (slot,op,half), j=0
    const signed char* gA = Aq + (size_t)(m0 + srow) * K + ((l8 ^ lr) << 4);
    const signed char* gB = Bt + (size_t)(n0 + srow) * K + ((l8 ^ lr) << 4);

    auto stage = [&](int slot, int op, int h, int tk) {
        signed char* l = smem + slot * 65536 + op * 32768 + h * 16384 + stoff;
        const signed char* g = (op ? gB : gA) + (size_t)(h * 128) * K + (size_t)tk * TILE_BK;
        async_copy16(g, l);
        async_copy16(g + (size_t)64 * K, l + 8192);
    };

    // ---- fragment reads: A[row = wr*128 + m*16 + ml][k = ks*64 + kq*16 + 0..15]
    const int axor = (ml & 7) << 4;
    const int c0 = (kq * 16) ^ axor;
    const int c1 = (64 + kq * 16) ^ axor;
    const int aBase = (wr * 128 + ml) * 128;
    const int bBase = 32768 + (wc * 64 + ml) * 128;

    int32x4 acc[8][4] = {};
    int32x4 a0[4][2], a1[4][2], b[4][2];

    auto rdA = [&](int32x4 (&dst)[4][2], int slotoff, int mb) {
#pragma unroll
        for (int mm = 0; mm < 4; ++mm) {
            const signed char* p = smem + slotoff + aBase + (mb + mm) * 2048;
            dst[mm][0] = *(const int32x4*)(p + c0);
            dst[mm][1] = *(const int32x4*)(p + c1);
        }
    };
    auto rdB2 = [&](int slotoff, int nb) {
#pragma unroll
        for (int nn = 0; nn < 2; ++nn) {
            const signed char* p = smem + slotoff + bBase + (nb + nn) * 2048;
            b[nb + nn][0] = *(const int32x4*)(p + c0);
            b[nb + nn][1] = *(const int32x4*)(p + c1);
        }
    };

    const int NI = K / (2 * TILE_BK); // 16 iterations, 2 K-tiles each
    const int S0 = 0, S1 = 65536;

    // prologue: tile0 -> s0 (8 loads), tile1.B -> s1 (4 loads); read RA0(s0)+RB01(s0).
    stage(0, 0, 0, 0); stage(0, 0, 1, 0); stage(0, 1, 0, 0); stage(0, 1, 1, 0);
    stage(1, 1, 0, 1); stage(1, 1, 1, 1);
    VMCNT(4);          // tile0's 8 landed; s1.B (4) in flight
    SBAR();
    rdA(a0, S0, 0);    // RA0(s0)
    rdB2(S0, 0);       // RB01(s0)

    for (int i = 0; i < NI - 1; ++i) {
        const int t1 = 2 * i + 1, t2 = 2 * i + 2, t3 = 2 * i + 3;

        // P1: QA(s0)
        rdA(a1, S0, 4);
        stage(1, 0, 0, t1);
        SBAR();
        MFMA_Q(a0, 0, 0);
        SBAR();
        // P2: QB(s0)
        rdB2(S0, 2);
        stage(1, 0, 1, t1);
        SBAR();
        MFMA_Q(a1, 4, 0);
        LGKM0();           // RB23(s0) drained before P3 stages s0.B
        VMCNT(4);          // s1.B (tile t1) landed for P3 reads
        SBAR();
        // P3: QC(s0)
        rdB2(S1, 0);
        stage(0, 1, 0, t2);
        SBAR();
        MFMA_Q(a0, 0, 2);
        VMCNT(2);          // s1.A (tile t1) landed for P4/P5 reads
        SBAR();
        // P4: QD(s0)
        rdA(a0, S1, 0);
        stage(0, 1, 1, t2);
        SBAR();
        MFMA_Q(a1, 4, 2);
        SBAR();
        // P5: QA(s1)
        rdA(a1, S1, 4);
        stage(0, 0, 0, t2);
        SBAR();
        MFMA_Q(a0, 0, 0);
        SBAR();
        // P6: QB(s1)
        rdB2(S1, 2);
        stage(0, 0, 1, t2);
        SBAR();
        MFMA_Q(a1, 4, 0);
        LGKM0();           // RB23(s1) drained before P7 stages s1.B
        VMCNT(4);          // s0.B (tile t2) landed for P7 reads
        SBAR();
        // P7: QC(s1)
        rdB2(S0, 0);
        stage(1, 1, 0, t3);
        SBAR();
        MFMA_Q(a0, 0, 2);
        VMCNT(2);          // s0.A (tile t2) landed for P8/P1' reads
        SBAR();
        // P8: QD(s1)
        rdA(a0, S0, 0);
        stage(1, 1, 1, t3);
        SBAR();
        MFMA_Q(a1, 4, 2);
        SBAR();
    }

    // ---- last iteration (tiles 2*NI-2 in s0, 2*NI-1 in s1): no s0'/t2/t3 work.
    {
        const int t1 = 2 * NI - 1;
        // P1
        rdA(a1, S0, 4);
        stage(1, 0, 0, t1);
        SBAR();
        MFMA_Q(a0, 0, 0);
        SBAR();
        // P2
        rdB2(S0, 2);
        stage(1, 0, 1, t1);
        SBAR();
        MFMA_Q(a1, 4, 0);
        VMCNT(4);          // s1.B (tile t1) landed
        SBAR();
        // P3
        rdB2(S1, 0);
        SBAR();
        MFMA_Q(a0, 0, 2);
        VMCNT(0);          // s1.A (tile t1) landed (final drain)
        SBAR();
        // P4
        rdA(a0, S1, 0);
        SBAR();
        MFMA_Q(a1, 4, 2);
        SBAR();
        // P5
        rdA(a1, S1, 4);
        SBAR();
        MFMA_Q(a0, 0, 0);
        SBAR();
        // P6
        rdB2(S1, 2);
        SBAR();
        MFMA_Q(a1, 4, 0);
        SBAR();
        // P7
        MFMA_Q(a0, 0, 2);
        SBAR();
        // P8
        MFMA_Q(a1, 4, 2);
    }

    // epilogue: C/D 16x16 layout col=lane&15, row=(lane>>4)*4+reg
    const int colb = n0 + wc * 64 + ml;
    const int rowb = m0 + wr * 128 + kq * 4;
#pragma unroll
    for (int n = 0; n < 4; ++n) {
        const int col = colb + n * 16;
        const float wsn = wscale[col];
        const float bsn = bias[col];
#pragma unroll
        for (int m = 0; m < 8; ++m) {
            const int row = rowb + m * 16;
            float* cp = C + (size_t)row * N + col;
#pragma unroll
            for (int r = 0; r < 4; ++r) {
                // match ref order: (c * a_scale) * w_scale + bias
                cp[(size_t)r * N] = ((float)acc[m][n][r] * ascale[row + r]) * wsn + bsn;
            }
        }
    }
}

extern "C" void kernel_launch(void* const* d_in, const int* in_sizes, int n_in,
                              void* d_out, int out_size, void* d_ws, size_t ws_size,
                              hipStream_t stream) {
    const float* x      = (const float*)d_in[0];
    const int*   wq     = (const int*)d_in[1];   // int8 values in int32 storage
    const float* wscale = (const float*)d_in[2];
    const float* bias   = (const float*)d_in[3];
    float* out          = (float*)d_out;

    const int N = in_sizes[2];
    const int K = in_sizes[1] / N;
    const int M = in_sizes[0] / K;

    // workspace layout: x_q [M*K] i8 | Bt [N*K] i8 | a_scale [M] f32  (~50.4 MB)
    char* ws = (char*)d_ws;
    signed char* xq = (signed char*)ws;
    signed char* bt = (signed char*)(ws + (size_t)M * K);
    float* ascale   = (float*)(ws + (size_t)M * K + (size_t)N * K);

    const int prepBlocks = M + (N >> 6) * (K >> 6);
    prep_kernel<<<prepBlocks, 256, 0, stream>>>(x, xq, ascale, wq, bt, K, N, M);
    gemm_i8_kernel<<<dim3(N / TILE_BN, M / TILE_BM), 512, 0, stream>>>(
        xq, bt, ascale, wscale, bias, out, M, N, K);
}

// Round 3
// 389.538 us; speedup vs baseline: 1.6343x; 1.6343x over previous
//
#include <hip/hip_runtime.h>

// QuantizedLinear: out[M,N] = (rowquant(x) . W_q) * a_scale[M] * w_scale[N] + bias[N]
// M=8192, K=4096, N=4096.  Three kernels:
//  1) quant_kernel:       per-row absmax -> a_scale, x_q int8 [M,K] (wave-coalesced)
//  2) transpose_pack:     W_q int32 [K,N] -> int8 [N,K] (k-contiguous for MFMA B)
//  3) gemm_i8_kernel:     256x256x128 tile, balanced 8-phase m201-style schedule,
//                         mfma_i32_16x16x64_i8, counted vmcnt, XOR-swizzled LDS,
//                         __launch_bounds__(512,1) (LDS limits to 1 block/CU anyway).

typedef int int32x4 __attribute__((ext_vector_type(4)));

#define TILE_BM 256
#define TILE_BN 256
#define TILE_BK 128   // int8 k-depth per K-tile (2 mfma k-steps of 64)

__device__ __forceinline__ void async_copy16(const void* g, void* l) {
    __builtin_amdgcn_global_load_lds(
        (const __attribute__((address_space(1))) unsigned int*)g,
        (__attribute__((address_space(3))) unsigned int*)l,
        16, 0, 0);
}

__device__ __forceinline__ int quant1(float x, float s) {
    float q = rintf(x / s);               // true division: bit-match np (x / a_scale)
    q = fminf(127.0f, fmaxf(-128.0f, q)); // np.clip(round, -128, 127)
    return (int)q;
}

// ---------------- kernel 1: per-row dynamic quantization ----------------
__global__ __launch_bounds__(256) void quant_kernel(
    const float* __restrict__ x, signed char* __restrict__ xq,
    float* __restrict__ ascale, int K)
{
    const int row = blockIdx.x;
    const int t = threadIdx.x;
    const float4* xr4 = (const float4*)(x + (size_t)row * K);

    float4 v[4];
    float mx = 0.0f;
#pragma unroll
    for (int i = 0; i < 4; ++i) {
        v[i] = xr4[i * 256 + t];
        mx = fmaxf(mx, fmaxf(fmaxf(fabsf(v[i].x), fabsf(v[i].y)),
                             fmaxf(fabsf(v[i].z), fabsf(v[i].w))));
    }
#pragma unroll
    for (int off = 32; off > 0; off >>= 1)
        mx = fmaxf(mx, __shfl_xor(mx, off, 64));
    __shared__ float wmax[4];
    if ((t & 63) == 0) wmax[t >> 6] = mx;
    __syncthreads();
    mx = fmaxf(fmaxf(wmax[0], wmax[1]), fmaxf(wmax[2], wmax[3]));

    const float s = fmaxf(mx / 127.0f, 1e-8f);
    if (t == 0) ascale[row] = s;

    int* xqr = (int*)(xq + (size_t)row * K);
#pragma unroll
    for (int i = 0; i < 4; ++i) {
        const int b0 = quant1(v[i].x, s);
        const int b1 = quant1(v[i].y, s);
        const int b2 = quant1(v[i].z, s);
        const int b3 = quant1(v[i].w, s);
        xqr[i * 256 + t] = (b0 & 255) | ((b1 & 255) << 8) | ((b2 & 255) << 16) | ((b3 & 255) << 24);
    }
}

// ---------------- kernel 2: transpose + pack weight ----------------
__global__ __launch_bounds__(256) void transpose_pack_kernel(
    const int* __restrict__ Bq, signed char* __restrict__ Bt, int K, int N)
{
    __shared__ int lds[64 * 17];
    const int t = threadIdx.x;
    const int n0 = blockIdx.x * 64;
    const int k0 = blockIdx.y * 64;

    const int r = t >> 4;
    const int ncol = (t & 15) * 4;

    const int* src = Bq + (size_t)(k0 + 4 * r) * N + n0 + ncol;
    const int4 u0 = *(const int4*)(src);
    const int4 u1 = *(const int4*)(src + N);
    const int4 u2 = *(const int4*)(src + 2 * (size_t)N);
    const int4 u3 = *(const int4*)(src + 3 * (size_t)N);

    lds[(ncol + 0) * 17 + r] = (u0.x & 255) | ((u1.x & 255) << 8) | ((u2.x & 255) << 16) | ((u3.x & 255) << 24);
    lds[(ncol + 1) * 17 + r] = (u0.y & 255) | ((u1.y & 255) << 8) | ((u2.y & 255) << 16) | ((u3.y & 255) << 24);
    lds[(ncol + 2) * 17 + r] = (u0.z & 255) | ((u1.z & 255) << 8) | ((u2.z & 255) << 16) | ((u3.z & 255) << 24);
    lds[(ncol + 3) * 17 + r] = (u0.w & 255) | ((u1.w & 255) << 8) | ((u2.w & 255) << 16) | ((u3.w & 255) << 24);
    __syncthreads();

    const int nl = t >> 2, ch = t & 3;
    int o[4];
#pragma unroll
    for (int i = 0; i < 4; ++i) o[i] = lds[nl * 17 + ch * 4 + i];
    *(int32x4*)(Bt + (size_t)(n0 + nl) * K + k0 + ch * 16) = *(const int32x4*)o;
}

// ---------------- kernel 3: int8 GEMM, 256x256 tile, balanced 8-phase ----------------
// 512 threads = 8 waves (2 M x 4 N); per-wave output 128x64 = 8x4 frags of 16x16.
// LDS 128 KiB: 2 slots x (A 32KB + B 32KB); slot0 = even K-tiles, slot1 = odd.
// Quadrant order per K-tile: QA=a(m0-3)*b01, QB=a(m0-3)*b23, QC=a(m4-7)*b23,
// QD=a(m4-7)*b01.  Single a[4][2] buffer (refilled P1/P3); b23[2][2] (P2/P6);
// b01 statically double-buffered b01a/b01b, prefetched ONE phase early (P4/P8) --
// the only cross-phase fragment (16 regs).  Reads/phase: 8,4,8,4,8,4,8,4.
// Per phase: {ds_read; stage 1 half; barrier; lgkm0; 16 MFMA (setprio); [vmcnt]; barrier}
//   P1 rd a(s0,lo)  | stage s1.B.h1(2i+1) | MFMA a*b01a
//   P2 rd b23(s0)   | stage s1.A.h0(2i+1) | MFMA a*b23
//   P3 rd a(s0,hi)  | stage s1.A.h1(2i+1) | MFMA a*b23  | vmcnt(4)
//   P4 rd b01b(s1)  | stage s0.B.h0(2i+2) | MFMA a*b01a | vmcnt(2)   (no lgkm0)
//   P5 rd a(s1,lo)  | stage s0.B.h1(2i+2) | MFMA a*b01b
//   P6 rd b23(s1)   | stage s0.A.h0(2i+2) | MFMA a*b23
//   P7 rd a(s1,hi)  | stage s0.A.h1(2i+2) | MFMA a*b23  | vmcnt(4)
//   P8 rd b01a(s0') | stage s1.B.h0(2i+3) | MFMA a*b01b | vmcnt(2)   (no lgkm0)
// vmcnt is counted, placed BEFORE the post-phase barrier (cross-wave rule:
// vmcnt -> barrier -> dependent ds_read): vmcnt(4)@P3 lands {P8',P1} = s1.B for P4;
// vmcnt(2)@P4 lands {P2,P3} = s1.A for P5/P7; vmcnt(4)@P7 lands {P4,P5} = s0'.B for
// P8; vmcnt(2)@P8 lands {P6,P7} = s0'.A for next P1/P3.  WAR: every stage target's
// last reader drained (lgkm0 + barrier) >=2 phases earlier (verified per phase).
// LDS swizzle: byte ^= ((row&7)<<4) on ds_read addr AND pre-applied on the global
// source chunk (global_load_lds writes linearly) -- same involution both sides.

#define SBAR() do { asm volatile("" ::: "memory"); __builtin_amdgcn_s_barrier(); asm volatile("" ::: "memory"); } while (0)
#define LGKM0() asm volatile("s_waitcnt lgkmcnt(0)" ::: "memory")
#define VMCNT(n) asm volatile("s_waitcnt vmcnt(" #n ")" ::: "memory")

#define MFMAQ(MB, BP, NB)                                                               \
    do {                                                                                \
        __builtin_amdgcn_s_setprio(1);                                                  \
        _Pragma("unroll") for (int mm = 0; mm < 4; ++mm) {                              \
            _Pragma("unroll") for (int nn = 0; nn < 2; ++nn) {                          \
                int32x4 v = acc[(MB) + mm][(NB) + nn];                                  \
                v = __builtin_amdgcn_mfma_i32_16x16x64_i8(a[mm][0], BP[nn][0], v, 0, 0, 0); \
                v = __builtin_amdgcn_mfma_i32_16x16x64_i8(a[mm][1], BP[nn][1], v, 0, 0, 0); \
                acc[(MB) + mm][(NB) + nn] = v;                                          \
            }                                                                           \
        }                                                                               \
        __builtin_amdgcn_s_setprio(0);                                                  \
    } while (0)

__global__ __launch_bounds__(512, 1) void gemm_i8_kernel(
    const signed char* __restrict__ Aq, const signed char* __restrict__ Bt,
    const float* __restrict__ ascale, const float* __restrict__ wscale,
    const float* __restrict__ bias, float* __restrict__ C,
    int M, int N, int K)
{
    __shared__ __align__(16) signed char smem[131072]; // [slot:2][A 32K | B 32K]

    const int t = threadIdx.x;
    const int lane = t & 63;
    const int w = t >> 6;            // 0..7
    const int wr = w >> 2;           // 0..1 (M)
    const int wc = w & 3;            // 0..3 (N)
    const int ml = lane & 15, kq = lane >> 4;
    const int lr = lane >> 3, l8 = lane & 7;

    // T1: XCD-aware block swizzle (nwg = 512, divisible by 8)
    const int nbx = gridDim.x;       // N/256
    int bid = blockIdx.y * nbx + blockIdx.x;
    const int nwg = nbx * gridDim.y;
    if ((nwg & 7) == 0) bid = (bid & 7) * (nwg >> 3) + (bid >> 3);
    const int m0 = (bid / nbx) * TILE_BM;
    const int n0 = (bid % nbx) * TILE_BN;

    // ---- staging: per half (128 rows x 128B = 16KB), thread does 2x16B loads.
    const int srow = w * 8 + lr;                 // 0..63
    const int stoff = srow * 128 + l8 * 16;      // within (slot,op,half), j=0
    const signed char* gA = Aq + (size_t)(m0 + srow) * K + ((l8 ^ lr) << 4);
    const signed char* gB = Bt + (size_t)(n0 + srow) * K + ((l8 ^ lr) << 4);

    auto stage = [&](int slot, int op, int h, int tk) {
        signed char* l = smem + slot * 65536 + op * 32768 + h * 16384 + stoff;
        const signed char* g = (op ? gB : gA) + (size_t)(h * 128) * K + (size_t)tk * TILE_BK;
        async_copy16(g, l);
        async_copy16(g + (size_t)64 * K, l + 8192);
    };

    // ---- fragment reads: row-major [256][128] per op; swizzled phys col
    const int axor = (ml & 7) << 4;
    const int c0 = (kq * 16) ^ axor;
    const int c1 = (64 + kq * 16) ^ axor;
    const int aBase = (wr * 128 + ml) * 128;
    const int bBase = 32768 + (wc * 64 + ml) * 128;

    int32x4 acc[8][4] = {};
    int32x4 a[4][2], b01a[2][2], b01b[2][2], b23[2][2];

    auto rdA = [&](int slotoff, int mb) {
#pragma unroll
        for (int mm = 0; mm < 4; ++mm) {
            const signed char* p = smem + slotoff + aBase + (mb + mm) * 2048;
            a[mm][0] = *(const int32x4*)(p + c0);
            a[mm][1] = *(const int32x4*)(p + c1);
        }
    };
    auto rdB = [&](int32x4 (&dst)[2][2], int slotoff, int nb) {
#pragma unroll
        for (int nn = 0; nn < 2; ++nn) {
            const signed char* p = smem + slotoff + bBase + (nb + nn) * 2048;
            dst[nn][0] = *(const int32x4*)(p + c0);
            dst[nn][1] = *(const int32x4*)(p + c1);
        }
    };

    const int NI = K / (2 * TILE_BK); // 16 iterations, 2 K-tiles each
    const int S0 = 0, S1 = 65536;

    // prologue: tile0 -> s0 (4 halves), tile1 -> s1.B.h0; then pre-read b01a(s0).
    stage(0, 1, 0, 0); stage(0, 1, 1, 0); stage(0, 0, 0, 0); stage(0, 0, 1, 0);
    stage(1, 1, 0, 1);
    VMCNT(2);          // s0's 8 loads landed; s1.B.h0 (2) in flight
    SBAR();
    rdB(b01a, S0, 0);

    for (int i = 0; i < NI - 1; ++i) {
        const int t1 = 2 * i + 1, t2 = 2 * i + 2, t3 = 2 * i + 3;

        // P1
        rdA(S0, 0);
        stage(1, 1, 1, t1);
        SBAR(); LGKM0();
        MFMAQ(0, b01a, 0);
        SBAR();
        // P2
        rdB(b23, S0, 2);
        stage(1, 0, 0, t1);
        SBAR(); LGKM0();
        MFMAQ(0, b23, 2);
        SBAR();
        // P3
        rdA(S0, 4);
        stage(1, 0, 1, t1);
        SBAR(); LGKM0();
        MFMAQ(4, b23, 2);
        VMCNT(4);                  // {P8-prev, P1} landed -> s1.B complete for P4
        SBAR();
        // P4 (b01b prefetch; its consumer is P5 -> no lgkm drain here)
        rdB(b01b, S1, 0);
        stage(0, 1, 0, t2);
        SBAR();
        MFMAQ(4, b01a, 0);
        VMCNT(2);                  // {P2, P3} landed -> s1.A complete for P5/P7
        SBAR();
        // P5
        rdA(S1, 0);
        stage(0, 1, 1, t2);
        SBAR(); LGKM0();
        MFMAQ(0, b01b, 0);
        SBAR();
        // P6
        rdB(b23, S1, 2);
        stage(0, 0, 0, t2);
        SBAR(); LGKM0();
        MFMAQ(0, b23, 2);
        SBAR();
        // P7
        rdA(S1, 4);
        stage(0, 0, 1, t2);
        SBAR(); LGKM0();
        MFMAQ(4, b23, 2);
        VMCNT(4);                  // {P4, P5} landed -> s0'.B complete for P8
        SBAR();
        // P8 (b01a prefetch for next iter's s0)
        rdB(b01a, S0, 0);
        stage(1, 1, 0, t3);
        SBAR();
        MFMAQ(4, b01b, 0);
        VMCNT(2);                  // {P6, P7} landed -> s0'.A complete for next P1/P3
        SBAR();
    }

    // ---- last iteration: tiles 2*NI-2 (s0), 2*NI-1 (s1); no t2/t3 staging.
    {
        const int t1 = 2 * NI - 1;
        // P1
        rdA(S0, 0);
        stage(1, 1, 1, t1);
        SBAR(); LGKM0();
        MFMAQ(0, b01a, 0);
        SBAR();
        // P2
        rdB(b23, S0, 2);
        stage(1, 0, 0, t1);
        SBAR(); LGKM0();
        MFMAQ(0, b23, 2);
        SBAR();
        // P3
        rdA(S0, 4);
        stage(1, 0, 1, t1);
        SBAR(); LGKM0();
        MFMAQ(4, b23, 2);
        VMCNT(4);                  // {P8-prev, P1} landed -> s1.B complete
        SBAR();
        // P4
        rdB(b01b, S1, 0);
        SBAR();
        MFMAQ(4, b01a, 0);
        VMCNT(0);                  // final drain: s1.A landed
        SBAR();
        // P5
        rdA(S1, 0);
        SBAR(); LGKM0();
        MFMAQ(0, b01b, 0);
        SBAR();
        // P6
        rdB(b23, S1, 2);
        SBAR(); LGKM0();
        MFMAQ(0, b23, 2);
        SBAR();
        // P7
        rdA(S1, 4);
        SBAR(); LGKM0();
        MFMAQ(4, b23, 2);
        SBAR();
        // P8
        LGKM0();
        MFMAQ(4, b01b, 0);
    }

    // epilogue: C/D 16x16 layout col=lane&15, row=(lane>>4)*4+reg
    const int colb = n0 + wc * 64 + ml;
    const int rowb = m0 + wr * 128 + kq * 4;
#pragma unroll
    for (int n = 0; n < 4; ++n) {
        const int col = colb + n * 16;
        const float wsn = wscale[col];
        const float bsn = bias[col];
#pragma unroll
        for (int m = 0; m < 8; ++m) {
            const int row = rowb + m * 16;
            float* cp = C + (size_t)row * N + col;
#pragma unroll
            for (int r = 0; r < 4; ++r) {
                // match ref order: (c * a_scale) * w_scale + bias
                cp[(size_t)r * N] = ((float)acc[m][n][r] * ascale[row + r]) * wsn + bsn;
            }
        }
    }
}

extern "C" void kernel_launch(void* const* d_in, const int* in_sizes, int n_in,
                              void* d_out, int out_size, void* d_ws, size_t ws_size,
                              hipStream_t stream) {
    const float* x      = (const float*)d_in[0];
    const int*   wq     = (const int*)d_in[1];   // int8 values in int32 storage
    const float* wscale = (const float*)d_in[2];
    const float* bias   = (const float*)d_in[3];
    float* out          = (float*)d_out;

    const int N = in_sizes[2];
    const int K = in_sizes[1] / N;
    const int M = in_sizes[0] / K;

    // workspace layout: x_q [M*K] i8 | Bt [N*K] i8 | a_scale [M] f32  (~50.4 MB)
    char* ws = (char*)d_ws;
    signed char* xq = (signed char*)ws;
    signed char* bt = (signed char*)(ws + (size_t)M * K);
    float* ascale   = (float*)(ws + (size_t)M * K + (size_t)N * K);

    quant_kernel<<<M, 256, 0, stream>>>(x, xq, ascale, K);
    transpose_pack_kernel<<<dim3(N / 64, K / 64), 256, 0, stream>>>(wq, bt, K, N);
    gemm_i8_kernel<<<dim3(N / TILE_BN, M / TILE_BM), 512, 0, stream>>>(
        xq, bt, ascale, wscale, bias, out, M, N, K);
}